// Round 5
// baseline (1085.759 us; speedup 1.0000x reference)
//
#include <hip/hip_runtime.h>

typedef _Float16 half8 __attribute__((ext_vector_type(8)));
typedef _Float16 half4 __attribute__((ext_vector_type(4)));
typedef float f32x4 __attribute__((ext_vector_type(4)));

#define HID 512
#define NCHUNK 2048
#define CPB 8       // chunks per persistent block
#define NBLK (NCHUNK / CPB)

// Repack conv_w [O=512][I=512][tap=2] fp32 -> MFMA-fragment-ordered fp16:
// Wf[((nt*32 + ks)*64 + lane)*8 + j] = W[n = nt*16 + (lane&15)][k = ks*32 + (lane>>4)*8 + j]
// where k = tap*512 + i. One 16x16x32 B-fragment = 1KB contiguous.
__global__ void prep_w_kernel(const float* __restrict__ conv_w, _Float16* __restrict__ Wf) {
  int o = blockIdx.x * blockDim.x + threadIdx.x;
  if (o >= HID * HID * 2) return;
  int j = o & 7;
  int lane = (o >> 3) & 63;
  int ks = (o >> 9) & 31;
  int nt = o >> 14;
  int n = nt * 16 + (lane & 15);
  int k = ks * 32 + (lane >> 4) * 8 + j;
  int tap = k >> 9;
  int i = k & 511;
  Wf[o] = (_Float16)conv_w[n * 1024 + i * 2 + tap];
}

// Persistent: one block per CU, CPB chunks each, 512 threads = 8 waves.
// LDS caps occupancy at 1 block/CU (8 waves, 2/SIMD), so a 256-VGPR budget is
// free -> __launch_bounds__(512, 1). (512,2) capped VGPRs at 128 and spilled.
// LDS XOR swizzle on row-major tiles: byte ^= ((row&7)<<4).
__global__ __launch_bounds__(512, 1) void fused_kernel(
    const float* __restrict__ x, const _Float16* __restrict__ Wf,
    const float* __restrict__ conv_b, const float* __restrict__ ln_g,
    const float* __restrict__ ln_b, float* __restrict__ out) {

  // xs: storage row s holds x[s-1]; rows 0 and 65 zero (conv boundary), written once.
  // ct: [key][d] after conv; after scores it is dead and reused as ctT[512 d][64 key].
  __shared__ __align__(16) _Float16 xs[66 * 512];
  __shared__ __align__(16) _Float16 ct[64 * 512];
  __shared__ __align__(16) float sc[64 * 64];       // scores^T staging, granule-swizzled
  __shared__ __align__(16) _Float16 P[64 * 64];     // softmax + I, swizzled
  __shared__ float rowpart[64 * 8 * 2];
  __shared__ float mustat[64 * 2];

  const int tid = threadIdx.x;
  const int blk = blockIdx.x;
  const int w = tid >> 6;
  const int l = tid & 63;
  const int l15 = l & 15;
  const int lq = l >> 4;
  const int j4 = l15 & 3;

  char* xsb = (char*)xs;
  char* ctb = (char*)ct;
  char* Pb  = (char*)P;
  char* scb = (char*)sc;

  const f32x4 fzero = {0.f, 0.f, 0.f, 0.f};

  // ---- per-block constants
  float cb[4], gg[4], bb[4];
#pragma unroll
  for (int ni = 0; ni < 4; ++ni) {
    int d = w * 64 + ni * 16 + l15;
    cb[ni] = conv_b[d];
    gg[ni] = ln_g[d];
    bb[ni] = ln_b[d];
  }

  // ---- W fragment pipeline (3-deep)
  half8 bW[3][4];
  auto loadB = [&](half8* bR, int ks) {
#pragma unroll
    for (int ni = 0; ni < 4; ++ni)
      bR[ni] = *(const half8*)(Wf + (size_t)(((w * 4 + ni) * 32 + ks) * 64 + l) * 8);
  };
  loadB(bW[0], 0);
  loadB(bW[1], 1);
  loadB(bW[2], 2);

  // ---- x prefetch: 16 dwordx4 per thread (f32), converted to 8 half8 (fp16)
  // at the end of the conv epilogue to shrink long-range liveness 64->32 regs.
  f32x4 pf[16];
  half8 ph[8];
  auto prefetch_issue = [&](const float* xg) {
#pragma unroll
    for (int i = 0; i < 8; ++i) {
      int jj = tid + i * 512;
      int t = jj >> 6;
      int d8 = jj & 63;
      const f32x4* src = (const f32x4*)(xg + t * HID + d8 * 8);
      pf[2 * i]     = __builtin_nontemporal_load(src);
      pf[2 * i + 1] = __builtin_nontemporal_load(src + 1);
    }
  };
  auto convert_pf = [&]() {
#pragma unroll
    for (int i = 0; i < 8; ++i) {
      f32x4 f0 = pf[2 * i];
      f32x4 f1 = pf[2 * i + 1];
      half8 h;
      h[0] = (_Float16)f0[0]; h[1] = (_Float16)f0[1]; h[2] = (_Float16)f0[2]; h[3] = (_Float16)f0[3];
      h[4] = (_Float16)f1[0]; h[5] = (_Float16)f1[1]; h[6] = (_Float16)f1[2]; h[7] = (_Float16)f1[3];
      ph[i] = h;
    }
  };
  auto write_xs = [&]() {
#pragma unroll
    for (int i = 0; i < 8; ++i) {
      int jj = tid + i * 512;
      int t = jj >> 6;
      int d8 = jj & 63;
      int srow = t + 1;
      *(half8*)(xsb + srow * 1024 + ((d8 * 16) ^ ((srow & 7) << 4))) = ph[i];
    }
  };

  // ---- block prologue: guard rows + stage chunk 0
  const int chunk0 = blk * CPB;
  if (tid < 128) {
    int r = (tid < 64) ? 0 : 65;
    int g = tid & 63;
    half8 z = {0, 0, 0, 0, 0, 0, 0, 0};
    *(half8*)(xsb + r * 1024 + g * 16) = z;   // swizzle-invariant zeros, written once
  }
  prefetch_issue(x + (size_t)chunk0 * (64 * HID));
  convert_pf();
  write_xs();
  __syncthreads();

  for (int cc = 0; cc < CPB; ++cc) {
    const int chunk = chunk0 + cc;
    const bool haveNext = (cc + 1 < CPB);
    const float* xgn = x + (size_t)(chunk + 1) * (64 * HID);

    // ---------- Phase 1: conv GEMM ct = relu(A[64x1024] @ W[1024x512] + b)
    f32x4 acc[4][4];
#pragma unroll
    for (int mi = 0; mi < 4; ++mi)
#pragma unroll
      for (int ni = 0; ni < 4; ++ni) acc[mi][ni] = fzero;

#pragma unroll
    for (int ks = 0; ks < 32; ++ks) {
      const int kc2 = (ks & 15) * 64 + lq * 16;
      const int rowoff = (ks < 16) ? 0 : 2;
      half8 a[4];
#pragma unroll
      for (int mi = 0; mi < 4; ++mi) {
        int srow = mi * 16 + l15 + rowoff;
        a[mi] = *(const half8*)(xsb + srow * 1024 + (kc2 ^ ((srow & 7) << 4)));
      }
      half8* bR = bW[ks % 3];
#pragma unroll
      for (int mi = 0; mi < 4; ++mi)
#pragma unroll
        for (int ni = 0; ni < 4; ++ni)
          acc[mi][ni] = __builtin_amdgcn_mfma_f32_16x16x32_f16(a[mi], bR[ni], acc[mi][ni], 0, 0, 0);
      if (ks < 29) loadB(bW[(ks + 3) % 3], ks + 3);
      if (ks == 28) {
        // x prefetch issued AFTER the last W load of this chunk: W vmcnt waits
        // (in-order retire) never force the slow HBM x loads to drain.
        if (haveNext) prefetch_issue(xgn);
        __builtin_amdgcn_sched_barrier(0);   // pin issue point
      }
    }

    // ---------- epilogue: bias+relu (kept in acc), ct[key][d] write via 4x4 shfl transpose
#pragma unroll
    for (int mi = 0; mi < 4; ++mi)
#pragma unroll
      for (int ni = 0; ni < 4; ++ni) {
        float v0 = fmaxf(acc[mi][ni][0] + cb[ni], 0.f);
        float v1 = fmaxf(acc[mi][ni][1] + cb[ni], 0.f);
        float v2 = fmaxf(acc[mi][ni][2] + cb[ni], 0.f);
        float v3 = fmaxf(acc[mi][ni][3] + cb[ni], 0.f);
        acc[mi][ni][0] = v0; acc[mi][ni][1] = v1;
        acc[mi][ni][2] = v2; acc[mi][ni][3] = v3;
        float t0 = __shfl_xor(v1, 1);
        float t1 = __shfl_xor(v0, 1);
        float t2 = __shfl_xor(v3, 1);
        float t3 = __shfl_xor(v2, 1);
        if (j4 & 1) { v0 = t0; v2 = t2; } else { v1 = t1; v3 = t3; }
        float u0 = __shfl_xor(v2, 2);
        float u1 = __shfl_xor(v3, 2);
        float u2 = __shfl_xor(v0, 2);
        float u3 = __shfl_xor(v1, 2);
        if (j4 & 2) { v0 = u0; v1 = u1; } else { v2 = u2; v3 = u3; }
        half4 h = {(_Float16)v0, (_Float16)v1, (_Float16)v2, (_Float16)v3};
        int key = mi * 16 + lq * 4 + j4;
        int dbase = w * 64 + ni * 16 + (l15 & ~3);
        *(half4*)(ctb + key * 1024 + ((dbase * 2) ^ ((key & 7) << 4))) = h;
      }
    // x loads have had ~1200 cyc of cover (ks29..31 + epilogue); convert now,
    // dropping long-range prefetch liveness to 32 VGPRs (ph).
    if (haveNext) convert_pf();
    // W ks=0..2 for next chunk (younger than x loads; consumed after B3 anyway)
    loadB(bW[0], 0);
    loadB(bW[1], 1);
    loadB(bW[2], 2);
    __syncthreads();   // B1: ct visible

    // ---------- Phase 2: scores^T[key][q] = (ct @ x^T) / sqrt(D)
    {
      const int mt = w & 3;
      const int nt0 = (w >> 2) * 2;
      f32x4 s0 = fzero, s1 = fzero;
      for (int ks = 0; ks < 16; ++ks) {
        int kb = ks * 64 + lq * 16;
        int key = mt * 16 + l15;
        half8 a = *(const half8*)(ctb + key * 1024 + (kb ^ ((key & 7) << 4)));
        int q0 = nt0 * 16 + l15;
        int sr0 = q0 + 1, sr1 = q0 + 17;
        half8 b0 = *(const half8*)(xsb + sr0 * 1024 + (kb ^ ((sr0 & 7) << 4)));
        half8 b1 = *(const half8*)(xsb + sr1 * 1024 + (kb ^ ((sr1 & 7) << 4)));
        s0 = __builtin_amdgcn_mfma_f32_16x16x32_f16(a, b0, s0, 0, 0, 0);
        s1 = __builtin_amdgcn_mfma_f32_16x16x32_f16(a, b1, s1, 0, 0, 0);
      }
      const float scale = 0.04419417382415922f;  // 1/sqrt(512)
#pragma unroll
      for (int r = 0; r < 4; ++r) { s0[r] *= scale; s1[r] *= scale; }
      int gran = mt * 4 + lq;
      int q0 = nt0 * 16 + l15, q1 = q0 + 16;
      *(f32x4*)(scb + q0 * 256 + ((gran * 16) ^ ((q0 & 15) << 4))) = s0;
      *(f32x4*)(scb + q1 * 256 + ((gran * 16) ^ ((q1 & 15) << 4))) = s1;
    }
    __syncthreads();   // B2: sc visible; ct/xs reads done -> both may be overwritten

    // ---------- Phase 3a: softmax rows -> P = softmax + I (fused residual)
    {
      int q = tid >> 3;
      int g = tid & 7;
      f32x4 va = *(const f32x4*)(scb + q * 256 + (((2 * g + 0) * 16) ^ ((q & 15) << 4)));
      f32x4 vb = *(const f32x4*)(scb + q * 256 + (((2 * g + 1) * 16) ^ ((q & 15) << 4)));
      float v[8] = {va[0], va[1], va[2], va[3], vb[0], vb[1], vb[2], vb[3]};
      float m = v[0];
#pragma unroll
      for (int i = 1; i < 8; ++i) m = fmaxf(m, v[i]);
      m = fmaxf(m, __shfl_xor(m, 1));
      m = fmaxf(m, __shfl_xor(m, 2));
      m = fmaxf(m, __shfl_xor(m, 4));
      float s = 0.f;
#pragma unroll
      for (int i = 0; i < 8; ++i) { v[i] = __expf(v[i] - m); s += v[i]; }
      s += __shfl_xor(s, 1);
      s += __shfl_xor(s, 2);
      s += __shfl_xor(s, 4);
      float inv = 1.f / s;
      half8 p;
#pragma unroll
      for (int i = 0; i < 8; ++i) {
        float pv = v[i] * inv + ((g * 8 + i == q) ? 1.f : 0.f);
        p[i] = (_Float16)pv;
      }
      *(half8*)(Pb + q * 128 + ((g * 16) ^ ((q & 7) << 4))) = p;
    }

    // ---------- Phase 3b: ctT[512 d][64 key] into (dead) ct region from live acc
#pragma unroll
    for (int mi = 0; mi < 4; ++mi)
#pragma unroll
      for (int ni = 0; ni < 4; ++ni) {
        int t0 = mi * 16 + lq * 4;
        int d = w * 64 + ni * 16 + l15;
        half4 h = {(_Float16)acc[mi][ni][0], (_Float16)acc[mi][ni][1],
                   (_Float16)acc[mi][ni][2], (_Float16)acc[mi][ni][3]};
        *(half4*)(ctb + d * 128 + ((t0 * 2) ^ ((d & 7) << 4))) = h;
      }

    // ---------- Phase 3c: stage next chunk's x into xs (fp16 regs -> LDS)
    if (haveNext) write_xs();
    __syncthreads();   // B3: P, ctT, xs(next) visible

    // ---------- Phase 4: (P+I) @ ct -> pacc[q][d], LN stats, pool
    f32x4 pacc[4][4];
#pragma unroll
    for (int mi = 0; mi < 4; ++mi)
#pragma unroll
      for (int ni = 0; ni < 4; ++ni) pacc[mi][ni] = fzero;

#pragma unroll
    for (int ks = 0; ks < 2; ++ks) {
      half8 a[4], b[4];
#pragma unroll
      for (int mi = 0; mi < 4; ++mi) {
        int q = mi * 16 + l15;
        a[mi] = *(const half8*)(Pb + q * 128 + (((ks * 4 + lq) * 16) ^ ((q & 7) << 4)));
      }
#pragma unroll
      for (int ni = 0; ni < 4; ++ni) {
        int d = w * 64 + ni * 16 + l15;
        b[ni] = *(const half8*)(ctb + d * 128 + (((ks * 4 + lq) * 16) ^ ((d & 7) << 4)));
      }
#pragma unroll
      for (int mi = 0; mi < 4; ++mi)
#pragma unroll
        for (int ni = 0; ni < 4; ++ni)
          pacc[mi][ni] = __builtin_amdgcn_mfma_f32_16x16x32_f16(a[mi], b[ni], pacc[mi][ni], 0, 0, 0);
    }

    // per-row LN partial sums over this wave's 64 d-columns
#pragma unroll
    for (int mi = 0; mi < 4; ++mi)
#pragma unroll
      for (int r = 0; r < 4; ++r) {
        float s1 = 0.f, s2 = 0.f;
#pragma unroll
        for (int ni = 0; ni < 4; ++ni) {
          float v = pacc[mi][ni][r];
          s1 += v;
          s2 += v * v;
        }
        s1 += __shfl_xor(s1, 1); s2 += __shfl_xor(s2, 1);
        s1 += __shfl_xor(s1, 2); s2 += __shfl_xor(s2, 2);
        s1 += __shfl_xor(s1, 4); s2 += __shfl_xor(s2, 4);
        s1 += __shfl_xor(s1, 8); s2 += __shfl_xor(s2, 8);
        if (l15 == 0) {
          int t = mi * 16 + lq * 4 + r;
          rowpart[(t * 8 + w) * 2 + 0] = s1;
          rowpart[(t * 8 + w) * 2 + 1] = s2;
        }
      }
    __syncthreads();   // B4

    {
      int row = tid >> 3, p = tid & 7;
      float s1 = rowpart[(row * 8 + p) * 2 + 0];
      float s2 = rowpart[(row * 8 + p) * 2 + 1];
      s1 += __shfl_xor(s1, 1); s2 += __shfl_xor(s2, 1);
      s1 += __shfl_xor(s1, 2); s2 += __shfl_xor(s2, 2);
      s1 += __shfl_xor(s1, 4); s2 += __shfl_xor(s2, 4);
      if (p == 0) {
        float mu = s1 * (1.f / 512.f);
        float var = s2 * (1.f / 512.f) - mu * mu;
        mustat[row * 2 + 0] = mu;
        mustat[row * 2 + 1] = rsqrtf(var + 1e-5f);
      }
    }
    __syncthreads();   // B5

    // pooled[d] = g[d] * (1/64) * sum_q (v[q][d]-mu[q])*rs[q] + b[d]
#pragma unroll
    for (int ni = 0; ni < 4; ++ni) {
      float s = 0.f;
#pragma unroll
      for (int mi = 0; mi < 4; ++mi)
#pragma unroll
        for (int r = 0; r < 4; ++r) {
          int t = mi * 16 + lq * 4 + r;
          s += (pacc[mi][ni][r] - mustat[t * 2]) * mustat[t * 2 + 1];
        }
      s += __shfl_xor(s, 16);
      s += __shfl_xor(s, 32);
      if (l < 16) {
        int d = w * 64 + ni * 16 + l;
        out[(size_t)chunk * 512 + d] = gg[ni] * (s * (1.f / 64.f)) + bb[ni];
      }
    }
  }
}

extern "C" void kernel_launch(void* const* d_in, const int* in_sizes, int n_in,
                              void* d_out, int out_size, void* d_ws, size_t ws_size,
                              hipStream_t stream) {
  const float* x      = (const float*)d_in[0];
  const float* conv_w = (const float*)d_in[1];
  const float* conv_b = (const float*)d_in[2];
  const float* ln_g   = (const float*)d_in[3];
  const float* ln_b   = (const float*)d_in[4];
  float* out = (float*)d_out;
  _Float16* Wf = (_Float16*)d_ws;   // 512*1024 fp16 = 1 MB, fragment-ordered

  prep_w_kernel<<<(HID * HID * 2 + 255) / 256, 256, 0, stream>>>(conv_w, Wf);
  fused_kernel<<<NBLK, 512, 0, stream>>>(x, Wf, conv_b, ln_g, ln_b, out);
}

// Round 6
// 385.856 us; speedup vs baseline: 2.8139x; 2.8139x over previous
//
#include <hip/hip_runtime.h>

typedef _Float16 half8 __attribute__((ext_vector_type(8)));
typedef _Float16 half4 __attribute__((ext_vector_type(4)));
typedef float f32x4 __attribute__((ext_vector_type(4)));

#define HID 512
#define NCHUNK 2048
#define CPB 8       // chunks per persistent block
#define NBLK (NCHUNK / CPB)

// Repack conv_w [O=512][I=512][tap=2] fp32 -> MFMA-fragment-ordered fp16:
// Wf[((nt*32 + ks)*64 + lane)*8 + j] = W[n = nt*16 + (lane&15)][k = ks*32 + (lane>>4)*8 + j]
// where k = tap*512 + i. One 16x16x32 B-fragment = 1KB contiguous.
__global__ void prep_w_kernel(const float* __restrict__ conv_w, _Float16* __restrict__ Wf) {
  int o = blockIdx.x * blockDim.x + threadIdx.x;
  if (o >= HID * HID * 2) return;
  int j = o & 7;
  int lane = (o >> 3) & 63;
  int ks = (o >> 9) & 31;
  int nt = o >> 14;
  int n = nt * 16 + (lane & 15);
  int k = ks * 32 + (lane >> 4) * 8 + j;
  int tap = k >> 9;
  int i = k & 511;
  Wf[o] = (_Float16)conv_w[n * 1024 + i * 2 + tap];
}

// Persistent: one block per CU, CPB chunks each, 512 threads = 8 waves.
// Conv W pipeline uses NAMED registers bA/bB (r2-proven, no scratch); x prefetch
// is a single static-unrolled 16-load burst issued once per chunk, outside loops.
// LDS XOR swizzle on row-major tiles: byte ^= ((row&7)<<4).
__global__ __launch_bounds__(512) void fused_kernel(
    const float* __restrict__ x, const _Float16* __restrict__ Wf,
    const float* __restrict__ conv_b, const float* __restrict__ ln_g,
    const float* __restrict__ ln_b, float* __restrict__ out) {

  // xs: storage row s holds x[s-1]; rows 0 and 65 zero (conv boundary), written once.
  // ct: [key][d] after conv; after scores it is dead and reused as ctT[512 d][64 key].
  __shared__ __align__(16) _Float16 xs[66 * 512];
  __shared__ __align__(16) _Float16 ct[64 * 512];
  __shared__ __align__(16) float sc[64 * 64];       // scores^T staging, granule-swizzled
  __shared__ __align__(16) _Float16 P[64 * 64];     // softmax + I, swizzled
  __shared__ float rowpart[64 * 8 * 2];
  __shared__ float mustat[64 * 2];

  const int tid = threadIdx.x;
  const int blk = blockIdx.x;
  const int w = tid >> 6;
  const int l = tid & 63;
  const int l15 = l & 15;
  const int lq = l >> 4;
  const int j4 = l15 & 3;

  char* xsb = (char*)xs;
  char* ctb = (char*)ct;
  char* Pb  = (char*)P;
  char* scb = (char*)sc;

  const f32x4 fzero = {0.f, 0.f, 0.f, 0.f};

  // ---- per-block constants
  float cb[4], gg[4], bb[4];
#pragma unroll
  for (int ni = 0; ni < 4; ++ni) {
    int d = w * 64 + ni * 16 + l15;
    cb[ni] = conv_b[d];
    gg[ni] = ln_g[d];
    bb[ni] = ln_b[d];
  }

  // ---- W fragment pipeline: NAMED 2-deep rotation (no indexed array -> no scratch)
  half8 bA[4], bB[4];
  auto loadB = [&](half8* bR, int ks) {
#pragma unroll
    for (int ni = 0; ni < 4; ++ni)
      bR[ni] = *(const half8*)(Wf + (size_t)(((w * 4 + ni) * 32 + ks) * 64 + l) * 8);
  };

  // ---- x prefetch: 16 dwordx4 per thread, issued once per chunk (static unroll)
  f32x4 pf[16];
  auto prefetch_issue = [&](const float* xg) {
#pragma unroll
    for (int i = 0; i < 8; ++i) {
      int jj = tid + i * 512;
      int t = jj >> 6;
      int d8 = jj & 63;
      const f32x4* src = (const f32x4*)(xg + t * HID + d8 * 8);
      pf[2 * i]     = __builtin_nontemporal_load(src);
      pf[2 * i + 1] = __builtin_nontemporal_load(src + 1);
    }
  };
  auto write_xs = [&]() {   // convert fp32 regs -> fp16, store swizzled
#pragma unroll
    for (int i = 0; i < 8; ++i) {
      int jj = tid + i * 512;
      int t = jj >> 6;
      int d8 = jj & 63;
      f32x4 f0 = pf[2 * i];
      f32x4 f1 = pf[2 * i + 1];
      half8 h;
      h[0] = (_Float16)f0[0]; h[1] = (_Float16)f0[1]; h[2] = (_Float16)f0[2]; h[3] = (_Float16)f0[3];
      h[4] = (_Float16)f1[0]; h[5] = (_Float16)f1[1]; h[6] = (_Float16)f1[2]; h[7] = (_Float16)f1[3];
      int srow = t + 1;
      *(half8*)(xsb + srow * 1024 + ((d8 * 16) ^ ((srow & 7) << 4))) = h;
    }
  };

  // ---- block prologue: guard rows + stage chunk 0 + warm W pipeline
  const int chunk0 = blk * CPB;
  if (tid < 128) {
    int r = (tid < 64) ? 0 : 65;
    int g = tid & 63;
    half8 z = {0, 0, 0, 0, 0, 0, 0, 0};
    *(half8*)(xsb + r * 1024 + g * 16) = z;   // swizzle-invariant zeros, written once
  }
  prefetch_issue(x + (size_t)chunk0 * (64 * HID));
  write_xs();
  loadB(bA, 0);
  loadB(bB, 1);
  __syncthreads();

  for (int cc = 0; cc < CPB; ++cc) {
    const int chunk = chunk0 + cc;
    const bool haveNext = (cc + 1 < CPB);
    const float* xgn = x + (size_t)(chunk + 1) * (64 * HID);

    // ---------- Phase 1: conv GEMM ct = relu(A[64x1024] @ W[1024x512] + b)
    // A[t][k] = (k<512) ? x[t-1][k] : x[t+1][k-512]  -> xs storage rows t / t+2.
    f32x4 acc[4][4];
#pragma unroll
    for (int mi = 0; mi < 4; ++mi)
#pragma unroll
      for (int ni = 0; ni < 4; ++ni) acc[mi][ni] = fzero;

    {
      auto conv_step = [&](int ks, half8* bR) {
        const int kc2 = (ks & 15) * 64 + lq * 16;
        const int rowoff = (ks < 16) ? 0 : 2;
        half8 a[4];
#pragma unroll
        for (int mi = 0; mi < 4; ++mi) {
          int srow = mi * 16 + l15 + rowoff;
          a[mi] = *(const half8*)(xsb + srow * 1024 + (kc2 ^ ((srow & 7) << 4)));
        }
#pragma unroll
        for (int mi = 0; mi < 4; ++mi)
#pragma unroll
          for (int ni = 0; ni < 4; ++ni)
            acc[mi][ni] = __builtin_amdgcn_mfma_f32_16x16x32_f16(a[mi], bR[ni], acc[mi][ni], 0, 0, 0);
      };
      for (int ks = 0; ks < 30; ks += 2) {
        conv_step(ks, bA);
        loadB(bA, ks + 2);
        conv_step(ks + 1, bB);
        loadB(bB, ks + 3);
      }
      conv_step(30, bA);
      conv_step(31, bB);
    }

    // ---- issue next chunk's x loads now: covered by epilogue+scores+softmax
    if (haveNext) prefetch_issue(xgn);
    __builtin_amdgcn_sched_barrier(0);   // don't let the loads sink toward use

    // ---------- epilogue: bias+relu (kept in acc), ct[key][d] write via 4x4 shfl transpose
#pragma unroll
    for (int mi = 0; mi < 4; ++mi)
#pragma unroll
      for (int ni = 0; ni < 4; ++ni) {
        float v0 = fmaxf(acc[mi][ni][0] + cb[ni], 0.f);
        float v1 = fmaxf(acc[mi][ni][1] + cb[ni], 0.f);
        float v2 = fmaxf(acc[mi][ni][2] + cb[ni], 0.f);
        float v3 = fmaxf(acc[mi][ni][3] + cb[ni], 0.f);
        acc[mi][ni][0] = v0; acc[mi][ni][1] = v1;
        acc[mi][ni][2] = v2; acc[mi][ni][3] = v3;
        float t0 = __shfl_xor(v1, 1);
        float t1 = __shfl_xor(v0, 1);
        float t2 = __shfl_xor(v3, 1);
        float t3 = __shfl_xor(v2, 1);
        if (j4 & 1) { v0 = t0; v2 = t2; } else { v1 = t1; v3 = t3; }
        float u0 = __shfl_xor(v2, 2);
        float u1 = __shfl_xor(v3, 2);
        float u2 = __shfl_xor(v0, 2);
        float u3 = __shfl_xor(v1, 2);
        if (j4 & 2) { v0 = u0; v1 = u1; } else { v2 = u2; v3 = u3; }
        half4 h = {(_Float16)v0, (_Float16)v1, (_Float16)v2, (_Float16)v3};
        int key = mi * 16 + lq * 4 + j4;
        int dbase = w * 64 + ni * 16 + (l15 & ~3);
        *(half4*)(ctb + key * 1024 + ((dbase * 2) ^ ((key & 7) << 4))) = h;
      }
    __syncthreads();   // B1: ct visible

    // ---------- Phase 2: scores^T[key][q] = (ct @ x^T) / sqrt(D)
    {
      const int mt = w & 3;
      const int nt0 = (w >> 2) * 2;
      f32x4 s0 = fzero, s1 = fzero;
      for (int ks = 0; ks < 16; ++ks) {
        int kb = ks * 64 + lq * 16;
        int key = mt * 16 + l15;
        half8 a = *(const half8*)(ctb + key * 1024 + (kb ^ ((key & 7) << 4)));
        int q0 = nt0 * 16 + l15;
        int sr0 = q0 + 1, sr1 = q0 + 17;
        half8 b0 = *(const half8*)(xsb + sr0 * 1024 + (kb ^ ((sr0 & 7) << 4)));
        half8 b1 = *(const half8*)(xsb + sr1 * 1024 + (kb ^ ((sr1 & 7) << 4)));
        s0 = __builtin_amdgcn_mfma_f32_16x16x32_f16(a, b0, s0, 0, 0, 0);
        s1 = __builtin_amdgcn_mfma_f32_16x16x32_f16(a, b1, s1, 0, 0, 0);
      }
      const float scale = 0.04419417382415922f;  // 1/sqrt(512)
#pragma unroll
      for (int r = 0; r < 4; ++r) { s0[r] *= scale; s1[r] *= scale; }
      int gran = mt * 4 + lq;
      int q0 = nt0 * 16 + l15, q1 = q0 + 16;
      *(f32x4*)(scb + q0 * 256 + ((gran * 16) ^ ((q0 & 15) << 4))) = s0;
      *(f32x4*)(scb + q1 * 256 + ((gran * 16) ^ ((q1 & 15) << 4))) = s1;
    }
    __syncthreads();   // B2: sc visible; ct/xs reads done -> both may be overwritten

    // ---------- Phase 3a: softmax rows -> P = softmax + I (fused residual)
    {
      int q = tid >> 3;
      int g = tid & 7;
      f32x4 va = *(const f32x4*)(scb + q * 256 + (((2 * g + 0) * 16) ^ ((q & 15) << 4)));
      f32x4 vb = *(const f32x4*)(scb + q * 256 + (((2 * g + 1) * 16) ^ ((q & 15) << 4)));
      float v[8] = {va[0], va[1], va[2], va[3], vb[0], vb[1], vb[2], vb[3]};
      float m = v[0];
#pragma unroll
      for (int i = 1; i < 8; ++i) m = fmaxf(m, v[i]);
      m = fmaxf(m, __shfl_xor(m, 1));
      m = fmaxf(m, __shfl_xor(m, 2));
      m = fmaxf(m, __shfl_xor(m, 4));
      float s = 0.f;
#pragma unroll
      for (int i = 0; i < 8; ++i) { v[i] = __expf(v[i] - m); s += v[i]; }
      s += __shfl_xor(s, 1);
      s += __shfl_xor(s, 2);
      s += __shfl_xor(s, 4);
      float inv = 1.f / s;
      half8 p;
#pragma unroll
      for (int i = 0; i < 8; ++i) {
        float pv = v[i] * inv + ((g * 8 + i == q) ? 1.f : 0.f);
        p[i] = (_Float16)pv;
      }
      *(half8*)(Pb + q * 128 + ((g * 16) ^ ((q & 7) << 4))) = p;
    }

    // ---------- Phase 3b: ctT[512 d][64 key] into (dead) ct region from live acc
#pragma unroll
    for (int mi = 0; mi < 4; ++mi)
#pragma unroll
      for (int ni = 0; ni < 4; ++ni) {
        int t0 = mi * 16 + lq * 4;
        int d = w * 64 + ni * 16 + l15;
        half4 h = {(_Float16)acc[mi][ni][0], (_Float16)acc[mi][ni][1],
                   (_Float16)acc[mi][ni][2], (_Float16)acc[mi][ni][3]};
        *(half4*)(ctb + d * 128 + ((t0 * 2) ^ ((d & 7) << 4))) = h;
      }

    // ---------- Phase 3c: stage next chunk's x into xs; then reload W (W loads
    // come AFTER the x-consuming waits so they stay in flight into next conv)
    if (haveNext) {
      write_xs();
      loadB(bA, 0);
      loadB(bB, 1);
    }
    __syncthreads();   // B3: P, ctT, xs(next) visible

    // ---------- Phase 4: (P+I) @ ct -> pacc[q][d], LN stats, pool
    f32x4 pacc[4][4];
#pragma unroll
    for (int mi = 0; mi < 4; ++mi)
#pragma unroll
      for (int ni = 0; ni < 4; ++ni) pacc[mi][ni] = fzero;

#pragma unroll
    for (int ks = 0; ks < 2; ++ks) {
      half8 a[4], b[4];
#pragma unroll
      for (int mi = 0; mi < 4; ++mi) {
        int q = mi * 16 + l15;
        a[mi] = *(const half8*)(Pb + q * 128 + (((ks * 4 + lq) * 16) ^ ((q & 7) << 4)));
      }
#pragma unroll
      for (int ni = 0; ni < 4; ++ni) {
        int d = w * 64 + ni * 16 + l15;
        b[ni] = *(const half8*)(ctb + d * 128 + (((ks * 4 + lq) * 16) ^ ((d & 7) << 4)));
      }
#pragma unroll
      for (int mi = 0; mi < 4; ++mi)
#pragma unroll
        for (int ni = 0; ni < 4; ++ni)
          pacc[mi][ni] = __builtin_amdgcn_mfma_f32_16x16x32_f16(a[mi], b[ni], pacc[mi][ni], 0, 0, 0);
    }

    // per-row LN partial sums over this wave's 64 d-columns
#pragma unroll
    for (int mi = 0; mi < 4; ++mi)
#pragma unroll
      for (int r = 0; r < 4; ++r) {
        float s1 = 0.f, s2 = 0.f;
#pragma unroll
        for (int ni = 0; ni < 4; ++ni) {
          float v = pacc[mi][ni][r];
          s1 += v;
          s2 += v * v;
        }
        s1 += __shfl_xor(s1, 1); s2 += __shfl_xor(s2, 1);
        s1 += __shfl_xor(s1, 2); s2 += __shfl_xor(s2, 2);
        s1 += __shfl_xor(s1, 4); s2 += __shfl_xor(s2, 4);
        s1 += __shfl_xor(s1, 8); s2 += __shfl_xor(s2, 8);
        if (l15 == 0) {
          int t = mi * 16 + lq * 4 + r;
          rowpart[(t * 8 + w) * 2 + 0] = s1;
          rowpart[(t * 8 + w) * 2 + 1] = s2;
        }
      }
    __syncthreads();   // B4

    {
      int row = tid >> 3, p = tid & 7;
      float s1 = rowpart[(row * 8 + p) * 2 + 0];
      float s2 = rowpart[(row * 8 + p) * 2 + 1];
      s1 += __shfl_xor(s1, 1); s2 += __shfl_xor(s2, 1);
      s1 += __shfl_xor(s1, 2); s2 += __shfl_xor(s2, 2);
      s1 += __shfl_xor(s1, 4); s2 += __shfl_xor(s2, 4);
      if (p == 0) {
        float mu = s1 * (1.f / 512.f);
        float var = s2 * (1.f / 512.f) - mu * mu;
        mustat[row * 2 + 0] = mu;
        mustat[row * 2 + 1] = rsqrtf(var + 1e-5f);
      }
    }
    __syncthreads();   // B5

    // pooled[d] = g[d] * (1/64) * sum_q (v[q][d]-mu[q])*rs[q] + b[d]
#pragma unroll
    for (int ni = 0; ni < 4; ++ni) {
      float s = 0.f;
#pragma unroll
      for (int mi = 0; mi < 4; ++mi)
#pragma unroll
        for (int r = 0; r < 4; ++r) {
          int t = mi * 16 + lq * 4 + r;
          s += (pacc[mi][ni][r] - mustat[t * 2]) * mustat[t * 2 + 1];
        }
      s += __shfl_xor(s, 16);
      s += __shfl_xor(s, 32);
      if (l < 16) {
        int d = w * 64 + ni * 16 + l;
        out[(size_t)chunk * 512 + d] = gg[ni] * (s * (1.f / 64.f)) + bb[ni];
      }
    }
  }
}

extern "C" void kernel_launch(void* const* d_in, const int* in_sizes, int n_in,
                              void* d_out, int out_size, void* d_ws, size_t ws_size,
                              hipStream_t stream) {
  const float* x      = (const float*)d_in[0];
  const float* conv_w = (const float*)d_in[1];
  const float* conv_b = (const float*)d_in[2];
  const float* ln_g   = (const float*)d_in[3];
  const float* ln_b   = (const float*)d_in[4];
  float* out = (float*)d_out;
  _Float16* Wf = (_Float16*)d_ws;   // 512*1024 fp16 = 1 MB, fragment-ordered

  prep_w_kernel<<<(HID * HID * 2 + 255) / 256, 256, 0, stream>>>(conv_w, Wf);
  fused_kernel<<<NBLK, 512, 0, stream>>>(x, Wf, conv_b, ln_g, ln_b, out);
}

// Round 7
// 339.006 us; speedup vs baseline: 3.2028x; 1.1382x over previous
//
#include <hip/hip_runtime.h>

typedef _Float16 half8 __attribute__((ext_vector_type(8)));
typedef _Float16 half4 __attribute__((ext_vector_type(4)));
typedef float f32x4 __attribute__((ext_vector_type(4)));

#define HID 512
#define NCHUNK 2048
#define CPB 8       // chunks per persistent block
#define NBLK (NCHUNK / CPB)

// Repack conv_w [O=512][I=512][tap=2] fp32 -> MFMA-fragment-ordered fp16:
// Wf[((nt*32 + ks)*64 + lane)*8 + j] = W[n = nt*16 + (lane&15)][k = ks*32 + (lane>>4)*8 + j]
// where k = tap*512 + i. One 16x16x32 B-fragment = 1KB contiguous.
__global__ void prep_w_kernel(const float* __restrict__ conv_w, _Float16* __restrict__ Wf) {
  int o = blockIdx.x * blockDim.x + threadIdx.x;
  if (o >= HID * HID * 2) return;
  int j = o & 7;
  int lane = (o >> 3) & 63;
  int ks = (o >> 9) & 31;
  int nt = o >> 14;
  int n = nt * 16 + (lane & 15);
  int k = ks * 32 + (lane >> 4) * 8 + j;
  int tap = k >> 9;
  int i = k & 511;
  Wf[o] = (_Float16)conv_w[n * 1024 + i * 2 + tap];
}

// Persistent: one block per CU, CPB chunks each, 512 threads = 8 waves.
// Register budget: 8-wave block -> 2 waves/SIMD -> 256 unified regs/wave.
// acc+pacc = 128 AGPRs -> arch-VGPR cap 128. x-prefetch therefore runs in TWO
// 32-reg halves (pf[8] reused) to keep peak arch demand < 128 (r6 spilled at 64).
// LDS XOR swizzle on row-major tiles: byte ^= ((row&7)<<4).
__global__ __launch_bounds__(512) void fused_kernel(
    const float* __restrict__ x, const _Float16* __restrict__ Wf,
    const float* __restrict__ conv_b, const float* __restrict__ ln_g,
    const float* __restrict__ ln_b, float* __restrict__ out) {

  // xs: storage row s holds x[s-1]; rows 0 and 65 zero (conv boundary), written once.
  // ct: [key][d] after conv; after scores it is dead and reused as ctT[512 d][64 key].
  __shared__ __align__(16) _Float16 xs[66 * 512];
  __shared__ __align__(16) _Float16 ct[64 * 512];
  __shared__ __align__(16) float sc[64 * 64];       // scores^T staging, granule-swizzled
  __shared__ __align__(16) _Float16 P[64 * 64];     // softmax + I, swizzled
  __shared__ float rowpart[64 * 8 * 2];
  __shared__ float mustat[64 * 2];

  const int tid = threadIdx.x;
  const int blk = blockIdx.x;
  const int w = tid >> 6;
  const int l = tid & 63;
  const int l15 = l & 15;
  const int lq = l >> 4;
  const int j4 = l15 & 3;

  char* xsb = (char*)xs;
  char* ctb = (char*)ct;
  char* Pb  = (char*)P;
  char* scb = (char*)sc;

  const f32x4 fzero = {0.f, 0.f, 0.f, 0.f};

  // ---- per-block constants
  float cb[4], gg[4], bb[4];
#pragma unroll
  for (int ni = 0; ni < 4; ++ni) {
    int d = w * 64 + ni * 16 + l15;
    cb[ni] = conv_b[d];
    gg[ni] = ln_g[d];
    bb[ni] = ln_b[d];
  }

  // ---- W fragment pipeline: NAMED 2-deep rotation (no indexed array -> no scratch)
  half8 bA[4], bB[4];
  auto loadB = [&](half8* bR, int ks) {
#pragma unroll
    for (int ni = 0; ni < 4; ++ni)
      bR[ni] = *(const half8*)(Wf + (size_t)(((w * 4 + ni) * 32 + ks) * 64 + l) * 8);
  };

  // ---- x prefetch in HALVES: 8 dwordx4 per thread per half (32 VGPRs, reused)
  f32x4 pf[8];
  auto prefetch_half = [&](const float* xg, int h) {
#pragma unroll
    for (int i = 0; i < 4; ++i) {
      int jj = tid + (h * 4 + i) * 512;
      int t = jj >> 6;
      int d8 = jj & 63;
      const f32x4* src = (const f32x4*)(xg + t * HID + d8 * 8);
      pf[2 * i]     = __builtin_nontemporal_load(src);
      pf[2 * i + 1] = __builtin_nontemporal_load(src + 1);
    }
  };
  auto write_xs_half = [&](int h) {   // convert fp32 regs -> fp16, store swizzled
#pragma unroll
    for (int i = 0; i < 4; ++i) {
      int jj = tid + (h * 4 + i) * 512;
      int t = jj >> 6;
      int d8 = jj & 63;
      f32x4 f0 = pf[2 * i];
      f32x4 f1 = pf[2 * i + 1];
      half8 hh;
      hh[0] = (_Float16)f0[0]; hh[1] = (_Float16)f0[1]; hh[2] = (_Float16)f0[2]; hh[3] = (_Float16)f0[3];
      hh[4] = (_Float16)f1[0]; hh[5] = (_Float16)f1[1]; hh[6] = (_Float16)f1[2]; hh[7] = (_Float16)f1[3];
      int srow = t + 1;
      *(half8*)(xsb + srow * 1024 + ((d8 * 16) ^ ((srow & 7) << 4))) = hh;
    }
  };

  // ---- block prologue: guard rows + stage chunk 0 + warm W pipeline
  const int chunk0 = blk * CPB;
  if (tid < 128) {
    int r = (tid < 64) ? 0 : 65;
    int g = tid & 63;
    half8 z = {0, 0, 0, 0, 0, 0, 0, 0};
    *(half8*)(xsb + r * 1024 + g * 16) = z;   // swizzle-invariant zeros, written once
  }
  {
    const float* xg0 = x + (size_t)chunk0 * (64 * HID);
    prefetch_half(xg0, 0);
    write_xs_half(0);
    prefetch_half(xg0, 1);
    write_xs_half(1);
  }
  loadB(bA, 0);
  loadB(bB, 1);
  __syncthreads();

  for (int cc = 0; cc < CPB; ++cc) {
    const int chunk = chunk0 + cc;
    const bool haveNext = (cc + 1 < CPB);
    const float* xgn = x + (size_t)(chunk + 1) * (64 * HID);

    // ---------- Phase 1: conv GEMM ct = relu(A[64x1024] @ W[1024x512] + b)
    // A[t][k] = (k<512) ? x[t-1][k] : x[t+1][k-512]  -> xs storage rows t / t+2.
    f32x4 acc[4][4];
#pragma unroll
    for (int mi = 0; mi < 4; ++mi)
#pragma unroll
      for (int ni = 0; ni < 4; ++ni) acc[mi][ni] = fzero;

    {
      auto conv_step = [&](int ks, half8* bR) {
        const int kc2 = (ks & 15) * 64 + lq * 16;
        const int rowoff = (ks < 16) ? 0 : 2;
        half8 a[4];
#pragma unroll
        for (int mi = 0; mi < 4; ++mi) {
          int srow = mi * 16 + l15 + rowoff;
          a[mi] = *(const half8*)(xsb + srow * 1024 + (kc2 ^ ((srow & 7) << 4)));
        }
#pragma unroll
        for (int mi = 0; mi < 4; ++mi)
#pragma unroll
          for (int ni = 0; ni < 4; ++ni)
            acc[mi][ni] = __builtin_amdgcn_mfma_f32_16x16x32_f16(a[mi], bR[ni], acc[mi][ni], 0, 0, 0);
      };
      for (int ks = 0; ks < 30; ks += 2) {
        conv_step(ks, bA);
        loadB(bA, ks + 2);
        conv_step(ks + 1, bB);
        loadB(bB, ks + 3);
      }
      conv_step(30, bA);
      conv_step(31, bB);
    }

    // ---- issue next chunk's x loads, HALF 0 (rows 0..31): covered by
    // epilogue + B1 + scores + B2 + softmax.
    if (haveNext) prefetch_half(xgn, 0);
    __builtin_amdgcn_sched_barrier(0);   // pin issue point

    // ---------- epilogue: bias+relu (kept in acc), ct[key][d] write via 4x4 shfl transpose
#pragma unroll
    for (int mi = 0; mi < 4; ++mi)
#pragma unroll
      for (int ni = 0; ni < 4; ++ni) {
        float v0 = fmaxf(acc[mi][ni][0] + cb[ni], 0.f);
        float v1 = fmaxf(acc[mi][ni][1] + cb[ni], 0.f);
        float v2 = fmaxf(acc[mi][ni][2] + cb[ni], 0.f);
        float v3 = fmaxf(acc[mi][ni][3] + cb[ni], 0.f);
        acc[mi][ni][0] = v0; acc[mi][ni][1] = v1;
        acc[mi][ni][2] = v2; acc[mi][ni][3] = v3;
        float t0 = __shfl_xor(v1, 1);
        float t1 = __shfl_xor(v0, 1);
        float t2 = __shfl_xor(v3, 1);
        float t3 = __shfl_xor(v2, 1);
        if (j4 & 1) { v0 = t0; v2 = t2; } else { v1 = t1; v3 = t3; }
        float u0 = __shfl_xor(v2, 2);
        float u1 = __shfl_xor(v3, 2);
        float u2 = __shfl_xor(v0, 2);
        float u3 = __shfl_xor(v1, 2);
        if (j4 & 2) { v0 = u0; v1 = u1; } else { v2 = u2; v3 = u3; }
        half4 h = {(_Float16)v0, (_Float16)v1, (_Float16)v2, (_Float16)v3};
        int key = mi * 16 + lq * 4 + j4;
        int dbase = w * 64 + ni * 16 + (l15 & ~3);
        *(half4*)(ctb + key * 1024 + ((dbase * 2) ^ ((key & 7) << 4))) = h;
      }
    __syncthreads();   // B1: ct visible

    // ---------- Phase 2: scores^T[key][q] = (ct @ x^T) / sqrt(D)
    {
      const int mt = w & 3;
      const int nt0 = (w >> 2) * 2;
      f32x4 s0 = fzero, s1 = fzero;
      for (int ks = 0; ks < 16; ++ks) {
        int kb = ks * 64 + lq * 16;
        int key = mt * 16 + l15;
        half8 a = *(const half8*)(ctb + key * 1024 + (kb ^ ((key & 7) << 4)));
        int q0 = nt0 * 16 + l15;
        int sr0 = q0 + 1, sr1 = q0 + 17;
        half8 b0 = *(const half8*)(xsb + sr0 * 1024 + (kb ^ ((sr0 & 7) << 4)));
        half8 b1 = *(const half8*)(xsb + sr1 * 1024 + (kb ^ ((sr1 & 7) << 4)));
        s0 = __builtin_amdgcn_mfma_f32_16x16x32_f16(a, b0, s0, 0, 0, 0);
        s1 = __builtin_amdgcn_mfma_f32_16x16x32_f16(a, b1, s1, 0, 0, 0);
      }
      const float scale = 0.04419417382415922f;  // 1/sqrt(512)
#pragma unroll
      for (int r = 0; r < 4; ++r) { s0[r] *= scale; s1[r] *= scale; }
      int gran = mt * 4 + lq;
      int q0 = nt0 * 16 + l15, q1 = q0 + 16;
      *(f32x4*)(scb + q0 * 256 + ((gran * 16) ^ ((q0 & 15) << 4))) = s0;
      *(f32x4*)(scb + q1 * 256 + ((gran * 16) ^ ((q1 & 15) << 4))) = s1;
    }
    __syncthreads();   // B2: sc visible; ct/xs reads done -> both may be overwritten

    // ---------- Phase 3a: softmax rows -> P = softmax + I (fused residual)
    {
      int q = tid >> 3;
      int g = tid & 7;
      f32x4 va = *(const f32x4*)(scb + q * 256 + (((2 * g + 0) * 16) ^ ((q & 15) << 4)));
      f32x4 vb = *(const f32x4*)(scb + q * 256 + (((2 * g + 1) * 16) ^ ((q & 15) << 4)));
      float v[8] = {va[0], va[1], va[2], va[3], vb[0], vb[1], vb[2], vb[3]};
      float m = v[0];
#pragma unroll
      for (int i = 1; i < 8; ++i) m = fmaxf(m, v[i]);
      m = fmaxf(m, __shfl_xor(m, 1));
      m = fmaxf(m, __shfl_xor(m, 2));
      m = fmaxf(m, __shfl_xor(m, 4));
      float s = 0.f;
#pragma unroll
      for (int i = 0; i < 8; ++i) { v[i] = __expf(v[i] - m); s += v[i]; }
      s += __shfl_xor(s, 1);
      s += __shfl_xor(s, 2);
      s += __shfl_xor(s, 4);
      float inv = 1.f / s;
      half8 p;
#pragma unroll
      for (int i = 0; i < 8; ++i) {
        float pv = v[i] * inv + ((g * 8 + i == q) ? 1.f : 0.f);
        p[i] = (_Float16)pv;
      }
      *(half8*)(Pb + q * 128 + ((g * 16) ^ ((q & 7) << 4))) = p;
    }

    // ---------- Phase 3b: ctT[512 d][64 key] into (dead) ct region from live acc
#pragma unroll
    for (int mi = 0; mi < 4; ++mi)
#pragma unroll
      for (int ni = 0; ni < 4; ++ni) {
        int t0 = mi * 16 + lq * 4;
        int d = w * 64 + ni * 16 + l15;
        half4 h = {(_Float16)acc[mi][ni][0], (_Float16)acc[mi][ni][1],
                   (_Float16)acc[mi][ni][2], (_Float16)acc[mi][ni][3]};
        *(half4*)(ctb + d * 128 + ((t0 * 2) ^ ((d & 7) << 4))) = h;
      }

    // ---------- Phase 3c: write x half 0 to xs; issue half 1 (reg reuse); reload W
    if (haveNext) {
      write_xs_half(0);
      prefetch_half(xgn, 1);   // consumed after B4; covered by B3 + PV + LN
      loadB(bA, 0);
      loadB(bB, 1);
    }
    __builtin_amdgcn_sched_barrier(0);
    __syncthreads();   // B3: P, ctT, xs half 0 visible

    // ---------- Phase 4: (P+I) @ ct -> pacc[q][d], LN stats, pool
    f32x4 pacc[4][4];
#pragma unroll
    for (int mi = 0; mi < 4; ++mi)
#pragma unroll
      for (int ni = 0; ni < 4; ++ni) pacc[mi][ni] = fzero;

#pragma unroll
    for (int ks = 0; ks < 2; ++ks) {
      half8 a[4], b[4];
#pragma unroll
      for (int mi = 0; mi < 4; ++mi) {
        int q = mi * 16 + l15;
        a[mi] = *(const half8*)(Pb + q * 128 + (((ks * 4 + lq) * 16) ^ ((q & 7) << 4)));
      }
#pragma unroll
      for (int ni = 0; ni < 4; ++ni) {
        int d = w * 64 + ni * 16 + l15;
        b[ni] = *(const half8*)(ctb + d * 128 + (((ks * 4 + lq) * 16) ^ ((d & 7) << 4)));
      }
#pragma unroll
      for (int mi = 0; mi < 4; ++mi)
#pragma unroll
        for (int ni = 0; ni < 4; ++ni)
          pacc[mi][ni] = __builtin_amdgcn_mfma_f32_16x16x32_f16(a[mi], b[ni], pacc[mi][ni], 0, 0, 0);
    }

    // per-row LN partial sums over this wave's 64 d-columns
#pragma unroll
    for (int mi = 0; mi < 4; ++mi)
#pragma unroll
      for (int r = 0; r < 4; ++r) {
        float s1 = 0.f, s2 = 0.f;
#pragma unroll
        for (int ni = 0; ni < 4; ++ni) {
          float v = pacc[mi][ni][r];
          s1 += v;
          s2 += v * v;
        }
        s1 += __shfl_xor(s1, 1); s2 += __shfl_xor(s2, 1);
        s1 += __shfl_xor(s1, 2); s2 += __shfl_xor(s2, 2);
        s1 += __shfl_xor(s1, 4); s2 += __shfl_xor(s2, 4);
        s1 += __shfl_xor(s1, 8); s2 += __shfl_xor(s2, 8);
        if (l15 == 0) {
          int t = mi * 16 + lq * 4 + r;
          rowpart[(t * 8 + w) * 2 + 0] = s1;
          rowpart[(t * 8 + w) * 2 + 1] = s2;
        }
      }
    __syncthreads();   // B4

    {
      int row = tid >> 3, p = tid & 7;
      float s1 = rowpart[(row * 8 + p) * 2 + 0];
      float s2 = rowpart[(row * 8 + p) * 2 + 1];
      s1 += __shfl_xor(s1, 1); s2 += __shfl_xor(s2, 1);
      s1 += __shfl_xor(s1, 2); s2 += __shfl_xor(s2, 2);
      s1 += __shfl_xor(s1, 4); s2 += __shfl_xor(s2, 4);
      if (p == 0) {
        float mu = s1 * (1.f / 512.f);
        float var = s2 * (1.f / 512.f) - mu * mu;
        mustat[row * 2 + 0] = mu;
        mustat[row * 2 + 1] = rsqrtf(var + 1e-5f);
      }
    }

    // ---------- write x half 1 to xs (visible to next conv after B5)
    if (haveNext) write_xs_half(1);
    __syncthreads();   // B5: mustat + xs half 1 visible

    // pooled[d] = g[d] * (1/64) * sum_q (v[q][d]-mu[q])*rs[q] + b[d]
#pragma unroll
    for (int ni = 0; ni < 4; ++ni) {
      float s = 0.f;
#pragma unroll
      for (int mi = 0; mi < 4; ++mi)
#pragma unroll
        for (int r = 0; r < 4; ++r) {
          int t = mi * 16 + lq * 4 + r;
          s += (pacc[mi][ni][r] - mustat[t * 2]) * mustat[t * 2 + 1];
        }
      s += __shfl_xor(s, 16);
      s += __shfl_xor(s, 32);
      if (l < 16) {
        int d = w * 64 + ni * 16 + l;
        out[(size_t)chunk * 512 + d] = gg[ni] * (s * (1.f / 64.f)) + bb[ni];
      }
    }
  }
}

extern "C" void kernel_launch(void* const* d_in, const int* in_sizes, int n_in,
                              void* d_out, int out_size, void* d_ws, size_t ws_size,
                              hipStream_t stream) {
  const float* x      = (const float*)d_in[0];
  const float* conv_w = (const float*)d_in[1];
  const float* conv_b = (const float*)d_in[2];
  const float* ln_g   = (const float*)d_in[3];
  const float* ln_b   = (const float*)d_in[4];
  float* out = (float*)d_out;
  _Float16* Wf = (_Float16*)d_ws;   // 512*1024 fp16 = 1 MB, fragment-ordered

  prep_w_kernel<<<(HID * HID * 2 + 255) / 256, 256, 0, stream>>>(conv_w, Wf);
  fused_kernel<<<NBLK, 512, 0, stream>>>(x, Wf, conv_b, ln_g, ln_b, out);
}

// Round 8
// 332.982 us; speedup vs baseline: 3.2607x; 1.0181x over previous
//
#include <hip/hip_runtime.h>

typedef _Float16 half8 __attribute__((ext_vector_type(8)));
typedef _Float16 half4 __attribute__((ext_vector_type(4)));
typedef float f32x4 __attribute__((ext_vector_type(4)));

#define HID 512
#define NCHUNK 2048
#define CPB 8       // chunks per persistent block
#define NBLK (NCHUNK / CPB)

// Repack conv_w [O=512][I=512][tap=2] fp32 -> MFMA-fragment-ordered fp16:
// Wf[((nt*32 + ks)*64 + lane)*8 + j] = W[n = nt*16 + (lane&15)][k = ks*32 + (lane>>4)*8 + j]
// where k = tap*512 + i. One 16x16x32 B-fragment = 1KB contiguous.
__global__ void prep_w_kernel(const float* __restrict__ conv_w, _Float16* __restrict__ Wf) {
  int o = blockIdx.x * blockDim.x + threadIdx.x;
  if (o >= HID * HID * 2) return;
  int j = o & 7;
  int lane = (o >> 3) & 63;
  int ks = (o >> 9) & 31;
  int nt = o >> 14;
  int n = nt * 16 + (lane & 15);
  int k = ks * 32 + (lane >> 4) * 8 + j;
  int tap = k >> 9;
  int i = k & 511;
  Wf[o] = (_Float16)conv_w[n * 1024 + i * 2 + tap];
}

// Persistent: one block per CU, CPB chunks each, 512 threads = 8 waves.
// Register budget: 8 waves -> 2 waves/SIMD -> 256 unified regs/wave; acc+pacc
// use 128 AGPR, so arch-VGPR cap is 128. x-prefetch runs in two 32-reg halves
// (plain loads: x is L3-resident across replays -- nontemporal killed that).
// W reload for the next chunk happens at loop END (only bA/bB live there).
// LDS XOR swizzle on row-major tiles: byte ^= ((row&7)<<4).
__global__ __launch_bounds__(512) void fused_kernel(
    const float* __restrict__ x, const _Float16* __restrict__ Wf,
    const float* __restrict__ conv_b, const float* __restrict__ ln_g,
    const float* __restrict__ ln_b, float* __restrict__ out) {

  // xs: storage row s holds x[s-1]; rows 0 and 65 zero (conv boundary), written once.
  // ct: [key][d] after conv; after scores it is dead and reused as ctT[512 d][64 key].
  __shared__ __align__(16) _Float16 xs[66 * 512];
  __shared__ __align__(16) _Float16 ct[64 * 512];
  __shared__ __align__(16) float sc[64 * 64];       // scores^T staging, granule-swizzled
  __shared__ __align__(16) _Float16 P[64 * 64];     // softmax + I, swizzled
  __shared__ float rowpart[64 * 8 * 2];
  __shared__ float mustat[64 * 2];

  const int tid = threadIdx.x;
  const int blk = blockIdx.x;
  const int w = tid >> 6;
  const int l = tid & 63;
  const int l15 = l & 15;
  const int lq = l >> 4;
  const int j4 = l15 & 3;

  char* xsb = (char*)xs;
  char* ctb = (char*)ct;
  char* Pb  = (char*)P;
  char* scb = (char*)sc;

  const f32x4 fzero = {0.f, 0.f, 0.f, 0.f};

  // ---- per-block constants
  float cb[4], gg[4], bb[4];
#pragma unroll
  for (int ni = 0; ni < 4; ++ni) {
    int d = w * 64 + ni * 16 + l15;
    cb[ni] = conv_b[d];
    gg[ni] = ln_g[d];
    bb[ni] = ln_b[d];
  }

  // ---- W fragment pipeline: NAMED 2-deep rotation (no indexed array -> no scratch)
  half8 bA[4], bB[4];
  auto loadB = [&](half8* bR, int ks) {
#pragma unroll
    for (int ni = 0; ni < 4; ++ni)
      bR[ni] = *(const half8*)(Wf + (size_t)(((w * 4 + ni) * 32 + ks) * 64 + l) * 8);
  };

  // ---- x prefetch in HALVES: 8 dwordx4 per thread per half (32 VGPRs, reused)
  f32x4 pf[8];
  auto prefetch_half = [&](const float* xg, int h) {
#pragma unroll
    for (int i = 0; i < 4; ++i) {
      int jj = tid + (h * 4 + i) * 512;
      int t = jj >> 6;
      int d8 = jj & 63;
      const f32x4* src = (const f32x4*)(xg + t * HID + d8 * 8);
      pf[2 * i]     = src[0];
      pf[2 * i + 1] = src[1];
    }
  };
  auto write_xs_half = [&](int h) {   // convert fp32 regs -> fp16, store swizzled
#pragma unroll
    for (int i = 0; i < 4; ++i) {
      int jj = tid + (h * 4 + i) * 512;
      int t = jj >> 6;
      int d8 = jj & 63;
      f32x4 f0 = pf[2 * i];
      f32x4 f1 = pf[2 * i + 1];
      half8 hh;
      hh[0] = (_Float16)f0[0]; hh[1] = (_Float16)f0[1]; hh[2] = (_Float16)f0[2]; hh[3] = (_Float16)f0[3];
      hh[4] = (_Float16)f1[0]; hh[5] = (_Float16)f1[1]; hh[6] = (_Float16)f1[2]; hh[7] = (_Float16)f1[3];
      int srow = t + 1;
      *(half8*)(xsb + srow * 1024 + ((d8 * 16) ^ ((srow & 7) << 4))) = hh;
    }
  };

  // ---- block prologue: guard rows + stage chunk 0 + warm W pipeline
  const int chunk0 = blk * CPB;
  if (tid < 128) {
    int r = (tid < 64) ? 0 : 65;
    int g = tid & 63;
    half8 z = {0, 0, 0, 0, 0, 0, 0, 0};
    *(half8*)(xsb + r * 1024 + g * 16) = z;   // swizzle-invariant zeros, written once
  }
  {
    const float* xg0 = x + (size_t)chunk0 * (64 * HID);
    prefetch_half(xg0, 0);
    write_xs_half(0);
    prefetch_half(xg0, 1);
    write_xs_half(1);
  }
  loadB(bA, 0);
  loadB(bB, 1);
  __syncthreads();

  for (int cc = 0; cc < CPB; ++cc) {
    const int chunk = chunk0 + cc;
    const bool haveNext = (cc + 1 < CPB);
    const float* xgn = x + (size_t)(chunk + 1) * (64 * HID);

    // ---------- Phase 1: conv GEMM ct = relu(A[64x1024] @ W[1024x512] + b)
    // A[t][k] = (k<512) ? x[t-1][k] : x[t+1][k-512]  -> xs storage rows t / t+2.
    f32x4 acc[4][4];
#pragma unroll
    for (int mi = 0; mi < 4; ++mi)
#pragma unroll
      for (int ni = 0; ni < 4; ++ni) acc[mi][ni] = fzero;

    {
      auto conv_step = [&](int ks, half8* bR) {
        const int kc2 = (ks & 15) * 64 + lq * 16;
        const int rowoff = (ks < 16) ? 0 : 2;
        half8 a[4];
#pragma unroll
        for (int mi = 0; mi < 4; ++mi) {
          int srow = mi * 16 + l15 + rowoff;
          a[mi] = *(const half8*)(xsb + srow * 1024 + (kc2 ^ ((srow & 7) << 4)));
        }
#pragma unroll
        for (int mi = 0; mi < 4; ++mi)
#pragma unroll
          for (int ni = 0; ni < 4; ++ni)
            acc[mi][ni] = __builtin_amdgcn_mfma_f32_16x16x32_f16(a[mi], bR[ni], acc[mi][ni], 0, 0, 0);
      };
      for (int ks = 0; ks < 30; ks += 2) {
        conv_step(ks, bA);
        loadB(bA, ks + 2);
        conv_step(ks + 1, bB);
        loadB(bB, ks + 3);
      }
      conv_step(30, bA);
      conv_step(31, bB);
    }

    // ---- issue next chunk's x loads, HALF 0 (rows 0..31): covered by
    // epilogue + B1 + scores + B2 + softmax.
    if (haveNext) prefetch_half(xgn, 0);
    __builtin_amdgcn_sched_barrier(0);   // pin issue point

    // ---------- epilogue: bias+relu (kept in acc), ct[key][d] write via 4x4 shfl transpose
#pragma unroll
    for (int mi = 0; mi < 4; ++mi)
#pragma unroll
      for (int ni = 0; ni < 4; ++ni) {
        float v0 = fmaxf(acc[mi][ni][0] + cb[ni], 0.f);
        float v1 = fmaxf(acc[mi][ni][1] + cb[ni], 0.f);
        float v2 = fmaxf(acc[mi][ni][2] + cb[ni], 0.f);
        float v3 = fmaxf(acc[mi][ni][3] + cb[ni], 0.f);
        acc[mi][ni][0] = v0; acc[mi][ni][1] = v1;
        acc[mi][ni][2] = v2; acc[mi][ni][3] = v3;
        float t0 = __shfl_xor(v1, 1);
        float t1 = __shfl_xor(v0, 1);
        float t2 = __shfl_xor(v3, 1);
        float t3 = __shfl_xor(v2, 1);
        if (j4 & 1) { v0 = t0; v2 = t2; } else { v1 = t1; v3 = t3; }
        float u0 = __shfl_xor(v2, 2);
        float u1 = __shfl_xor(v3, 2);
        float u2 = __shfl_xor(v0, 2);
        float u3 = __shfl_xor(v1, 2);
        if (j4 & 2) { v0 = u0; v1 = u1; } else { v2 = u2; v3 = u3; }
        half4 h = {(_Float16)v0, (_Float16)v1, (_Float16)v2, (_Float16)v3};
        int key = mi * 16 + lq * 4 + j4;
        int dbase = w * 64 + ni * 16 + (l15 & ~3);
        *(half4*)(ctb + key * 1024 + ((dbase * 2) ^ ((key & 7) << 4))) = h;
      }
    __syncthreads();   // B1: ct visible

    // ---------- Phase 2: scores^T[key][q] = (ct @ x^T) / sqrt(D)
    {
      const int mt = w & 3;
      const int nt0 = (w >> 2) * 2;
      f32x4 s0 = fzero, s1 = fzero;
      for (int ks = 0; ks < 16; ++ks) {
        int kb = ks * 64 + lq * 16;
        int key = mt * 16 + l15;
        half8 a = *(const half8*)(ctb + key * 1024 + (kb ^ ((key & 7) << 4)));
        int q0 = nt0 * 16 + l15;
        int sr0 = q0 + 1, sr1 = q0 + 17;
        half8 b0 = *(const half8*)(xsb + sr0 * 1024 + (kb ^ ((sr0 & 7) << 4)));
        half8 b1 = *(const half8*)(xsb + sr1 * 1024 + (kb ^ ((sr1 & 7) << 4)));
        s0 = __builtin_amdgcn_mfma_f32_16x16x32_f16(a, b0, s0, 0, 0, 0);
        s1 = __builtin_amdgcn_mfma_f32_16x16x32_f16(a, b1, s1, 0, 0, 0);
      }
      const float scale = 0.04419417382415922f;  // 1/sqrt(512)
#pragma unroll
      for (int r = 0; r < 4; ++r) { s0[r] *= scale; s1[r] *= scale; }
      int gran = mt * 4 + lq;
      int q0 = nt0 * 16 + l15, q1 = q0 + 16;
      *(f32x4*)(scb + q0 * 256 + ((gran * 16) ^ ((q0 & 15) << 4))) = s0;
      *(f32x4*)(scb + q1 * 256 + ((gran * 16) ^ ((q1 & 15) << 4))) = s1;
    }
    __syncthreads();   // B2: sc visible; ct/xs reads done -> both may be overwritten

    // ---------- Phase 3a: softmax rows -> P = softmax + I (fused residual)
    {
      int q = tid >> 3;
      int g = tid & 7;
      f32x4 va = *(const f32x4*)(scb + q * 256 + (((2 * g + 0) * 16) ^ ((q & 15) << 4)));
      f32x4 vb = *(const f32x4*)(scb + q * 256 + (((2 * g + 1) * 16) ^ ((q & 15) << 4)));
      float v[8] = {va[0], va[1], va[2], va[3], vb[0], vb[1], vb[2], vb[3]};
      float m = v[0];
#pragma unroll
      for (int i = 1; i < 8; ++i) m = fmaxf(m, v[i]);
      m = fmaxf(m, __shfl_xor(m, 1));
      m = fmaxf(m, __shfl_xor(m, 2));
      m = fmaxf(m, __shfl_xor(m, 4));
      float s = 0.f;
#pragma unroll
      for (int i = 0; i < 8; ++i) { v[i] = __expf(v[i] - m); s += v[i]; }
      s += __shfl_xor(s, 1);
      s += __shfl_xor(s, 2);
      s += __shfl_xor(s, 4);
      float inv = 1.f / s;
      half8 p;
#pragma unroll
      for (int i = 0; i < 8; ++i) {
        float pv = v[i] * inv + ((g * 8 + i == q) ? 1.f : 0.f);
        p[i] = (_Float16)pv;
      }
      *(half8*)(Pb + q * 128 + ((g * 16) ^ ((q & 7) << 4))) = p;
    }

    // ---------- Phase 3b: ctT[512 d][64 key] into (dead) ct region from live acc
#pragma unroll
    for (int mi = 0; mi < 4; ++mi)
#pragma unroll
      for (int ni = 0; ni < 4; ++ni) {
        int t0 = mi * 16 + lq * 4;
        int d = w * 64 + ni * 16 + l15;
        half4 h = {(_Float16)acc[mi][ni][0], (_Float16)acc[mi][ni][1],
                   (_Float16)acc[mi][ni][2], (_Float16)acc[mi][ni][3]};
        *(half4*)(ctb + d * 128 + ((t0 * 2) ^ ((d & 7) << 4))) = h;
      }

    // ---------- Phase 3c: write x half 0 to xs; issue half 1 (reg reuse)
    if (haveNext) {
      write_xs_half(0);
      prefetch_half(xgn, 1);   // consumed after B4; covered by B3 + PV + LN
    }
    __builtin_amdgcn_sched_barrier(0);
    __syncthreads();   // B3: P, ctT, xs half 0 visible

    // ---------- Phase 4: (P+I) @ ct -> pacc[q][d], LN stats, pool
    f32x4 pacc[4][4];
#pragma unroll
    for (int mi = 0; mi < 4; ++mi)
#pragma unroll
      for (int ni = 0; ni < 4; ++ni) pacc[mi][ni] = fzero;

#pragma unroll
    for (int ks = 0; ks < 2; ++ks) {
      half8 a[4], b[4];
#pragma unroll
      for (int mi = 0; mi < 4; ++mi) {
        int q = mi * 16 + l15;
        a[mi] = *(const half8*)(Pb + q * 128 + (((ks * 4 + lq) * 16) ^ ((q & 7) << 4)));
      }
#pragma unroll
      for (int ni = 0; ni < 4; ++ni) {
        int d = w * 64 + ni * 16 + l15;
        b[ni] = *(const half8*)(ctb + d * 128 + (((ks * 4 + lq) * 16) ^ ((d & 7) << 4)));
      }
#pragma unroll
      for (int mi = 0; mi < 4; ++mi)
#pragma unroll
        for (int ni = 0; ni < 4; ++ni)
          pacc[mi][ni] = __builtin_amdgcn_mfma_f32_16x16x32_f16(a[mi], b[ni], pacc[mi][ni], 0, 0, 0);
    }

    // per-row LN partial sums over this wave's 64 d-columns
#pragma unroll
    for (int mi = 0; mi < 4; ++mi)
#pragma unroll
      for (int r = 0; r < 4; ++r) {
        float s1 = 0.f, s2 = 0.f;
#pragma unroll
        for (int ni = 0; ni < 4; ++ni) {
          float v = pacc[mi][ni][r];
          s1 += v;
          s2 += v * v;
        }
        s1 += __shfl_xor(s1, 1); s2 += __shfl_xor(s2, 1);
        s1 += __shfl_xor(s1, 2); s2 += __shfl_xor(s2, 2);
        s1 += __shfl_xor(s1, 4); s2 += __shfl_xor(s2, 4);
        s1 += __shfl_xor(s1, 8); s2 += __shfl_xor(s2, 8);
        if (l15 == 0) {
          int t = mi * 16 + lq * 4 + r;
          rowpart[(t * 8 + w) * 2 + 0] = s1;
          rowpart[(t * 8 + w) * 2 + 1] = s2;
        }
      }
    __syncthreads();   // B4

    {
      int row = tid >> 3, p = tid & 7;
      float s1 = rowpart[(row * 8 + p) * 2 + 0];
      float s2 = rowpart[(row * 8 + p) * 2 + 1];
      s1 += __shfl_xor(s1, 1); s2 += __shfl_xor(s2, 1);
      s1 += __shfl_xor(s1, 2); s2 += __shfl_xor(s2, 2);
      s1 += __shfl_xor(s1, 4); s2 += __shfl_xor(s2, 4);
      if (p == 0) {
        float mu = s1 * (1.f / 512.f);
        float var = s2 * (1.f / 512.f) - mu * mu;
        mustat[row * 2 + 0] = mu;
        mustat[row * 2 + 1] = rsqrtf(var + 1e-5f);
      }
    }

    // ---------- write x half 1 to xs (visible to next conv after B5)
    if (haveNext) write_xs_half(1);
    __syncthreads();   // B5: mustat + xs half 1 visible

    // pooled[d] = g[d] * (1/64) * sum_q (v[q][d]-mu[q])*rs[q] + b[d]
#pragma unroll
    for (int ni = 0; ni < 4; ++ni) {
      float s = 0.f;
#pragma unroll
      for (int mi = 0; mi < 4; ++mi)
#pragma unroll
        for (int r = 0; r < 4; ++r) {
          int t = mi * 16 + lq * 4 + r;
          s += (pacc[mi][ni][r] - mustat[t * 2]) * mustat[t * 2 + 1];
        }
      s += __shfl_xor(s, 16);
      s += __shfl_xor(s, 32);
      if (l < 16) {
        int d = w * 64 + ni * 16 + l;
        out[(size_t)chunk * 512 + d] = gg[ni] * (s * (1.f / 64.f)) + bb[ni];
      }
    }

    // ---------- loop tail: warm W pipeline for next chunk (only bA/bB live here)
    if (haveNext) {
      loadB(bA, 0);
      loadB(bB, 1);
    }
  }
}

extern "C" void kernel_launch(void* const* d_in, const int* in_sizes, int n_in,
                              void* d_out, int out_size, void* d_ws, size_t ws_size,
                              hipStream_t stream) {
  const float* x      = (const float*)d_in[0];
  const float* conv_w = (const float*)d_in[1];
  const float* conv_b = (const float*)d_in[2];
  const float* ln_g   = (const float*)d_in[3];
  const float* ln_b   = (const float*)d_in[4];
  float* out = (float*)d_out;
  _Float16* Wf = (_Float16*)d_ws;   // 512*1024 fp16 = 1 MB, fragment-ordered

  prep_w_kernel<<<(HID * HID * 2 + 255) / 256, 256, 0, stream>>>(conv_w, Wf);
  fused_kernel<<<NBLK, 512, 0, stream>>>(x, Wf, conv_b, ln_g, ln_b, out);
}

// Round 9
// 232.721 us; speedup vs baseline: 4.6655x; 1.4308x over previous
//
#include <hip/hip_runtime.h>

typedef _Float16 half8 __attribute__((ext_vector_type(8)));
typedef _Float16 half4 __attribute__((ext_vector_type(4)));
typedef float f32x4 __attribute__((ext_vector_type(4)));

#define HID 512
#define NCHUNK 2048

// Repack conv_w [O=512][I=512][tap=2] fp32 -> MFMA-fragment-ordered fp16:
// Wf[((nt*32 + ks)*64 + lane)*8 + j] = W[n = nt*16 + (lane&15)][k = ks*32 + (lane>>4)*8 + j]
// where k = tap*512 + i. One 16x16x32 B-fragment = 1KB contiguous.
__global__ void prep_w_kernel(const float* __restrict__ conv_w, _Float16* __restrict__ Wf) {
  int o = blockIdx.x * blockDim.x + threadIdx.x;
  if (o >= HID * HID * 2) return;
  int j = o & 7;
  int lane = (o >> 3) & 63;
  int ks = (o >> 9) & 31;
  int nt = o >> 14;
  int n = nt * 16 + (lane & 15);
  int k = ks * 32 + (lane >> 4) * 8 + j;
  int tap = k >> 9;
  int i = k & 511;
  Wf[o] = (_Float16)conv_w[n * 1024 + i * 2 + tap];
}

// One block per chunk (r2 structure — measured best, 227us, no spill), 512 thr.
// W fragments stream from L2/L3 through a 4-deep NAMED register pipeline
// (bA..bD): each load gets ~3 k-steps (~450cyc) of MFMA cover.
// LDS XOR swizzle on row-major tiles: byte ^= ((row&7)<<4).
__global__ __launch_bounds__(512) void fused_kernel(
    const float* __restrict__ x, const _Float16* __restrict__ Wf,
    const float* __restrict__ conv_b, const float* __restrict__ ln_g,
    const float* __restrict__ ln_b, float* __restrict__ out) {

  // xs: storage row s holds x[s-1]; rows 0 and 65 zero (conv boundary).
  // ct: [key][d] after conv; after scores it is dead and reused as ctT[512 d][64 key].
  __shared__ __align__(16) _Float16 xs[66 * 512];
  __shared__ __align__(16) _Float16 ct[64 * 512];
  __shared__ __align__(16) float sc[64 * 64];       // scores^T staging, granule-swizzled
  __shared__ __align__(16) _Float16 P[64 * 64];     // softmax + I, swizzled
  __shared__ float rowpart[64 * 8 * 2];
  __shared__ float mustat[64 * 2];

  const int tid = threadIdx.x;
  const int blk = blockIdx.x;
  const int w = tid >> 6;
  const int l = tid & 63;
  const int l15 = l & 15;
  const int lq = l >> 4;
  const int j4 = l15 & 3;

  char* xsb = (char*)xs;
  char* ctb = (char*)ct;
  char* Pb  = (char*)P;
  char* scb = (char*)sc;

  const f32x4 fzero = {0.f, 0.f, 0.f, 0.f};

  // ---- W fragment pipeline: 4 NAMED buffers (no indexed array -> no scratch)
  half8 bA[4], bB[4], bC[4], bD[4];
  auto loadB = [&](half8* bR, int ks) {
#pragma unroll
    for (int ni = 0; ni < 4; ++ni)
      bR[ni] = *(const half8*)(Wf + (size_t)(((w * 4 + ni) * 32 + ks) * 64 + l) * 8);
  };
  // warm the pipeline early — these retire while we stage x
  loadB(bA, 0);
  loadB(bB, 1);
  loadB(bC, 2);
  loadB(bD, 3);

  // ---------- Phase 0: stage x chunk -> LDS fp16 (swizzled), zero guard rows
  {
    const float* xg = x + (size_t)blk * (64 * HID);
#pragma unroll
    for (int i = 0; i < 8; ++i) {
      int jj = tid + i * 512;
      int t = jj >> 6;
      int d8 = jj & 63;
      const f32x4* src = (const f32x4*)(xg + t * HID + d8 * 8);
      f32x4 f0 = src[0];
      f32x4 f1 = src[1];
      half8 h;
      h[0] = (_Float16)f0[0]; h[1] = (_Float16)f0[1]; h[2] = (_Float16)f0[2]; h[3] = (_Float16)f0[3];
      h[4] = (_Float16)f1[0]; h[5] = (_Float16)f1[1]; h[6] = (_Float16)f1[2]; h[7] = (_Float16)f1[3];
      int srow = t + 1;
      *(half8*)(xsb + srow * 1024 + ((d8 * 16) ^ ((srow & 7) << 4))) = h;
    }
    if (tid < 128) {
      int r = (tid < 64) ? 0 : 65;
      int g = tid & 63;
      half8 z = {0, 0, 0, 0, 0, 0, 0, 0};
      *(half8*)(xsb + r * 1024 + g * 16) = z;   // swizzle-invariant zeros
    }
  }
  __syncthreads();

  // ---------- Phase 1: conv GEMM ct = relu(A[64x1024] @ W[1024x512] + b)
  // A[t][k] = (k<512) ? x[t-1][k] : x[t+1][k-512]  -> xs storage rows t / t+2.
  f32x4 acc[4][4];
#pragma unroll
  for (int mi = 0; mi < 4; ++mi)
#pragma unroll
    for (int ni = 0; ni < 4; ++ni) acc[mi][ni] = fzero;

  {
    auto conv_step = [&](int ks, half8* bR) {
      const int kc2 = (ks & 15) * 64 + lq * 16;
      const int rowoff = (ks < 16) ? 0 : 2;
      half8 a[4];
#pragma unroll
      for (int mi = 0; mi < 4; ++mi) {
        int srow = mi * 16 + l15 + rowoff;
        a[mi] = *(const half8*)(xsb + srow * 1024 + (kc2 ^ ((srow & 7) << 4)));
      }
#pragma unroll
      for (int mi = 0; mi < 4; ++mi)
#pragma unroll
        for (int ni = 0; ni < 4; ++ni)
          acc[mi][ni] = __builtin_amdgcn_mfma_f32_16x16x32_f16(a[mi], bR[ni], acc[mi][ni], 0, 0, 0);
    };
#pragma unroll
    for (int ks = 0; ks < 28; ks += 4) {
      conv_step(ks + 0, bA);
      loadB(bA, ks + 4);
      conv_step(ks + 1, bB);
      loadB(bB, ks + 5);
      conv_step(ks + 2, bC);
      loadB(bC, ks + 6);
      conv_step(ks + 3, bD);
      loadB(bD, ks + 7);
    }
    conv_step(28, bA);
    conv_step(29, bB);
    conv_step(30, bC);
    conv_step(31, bD);
  }

  // ---------- Phase 1 epilogue: bias+relu (kept in acc), write ct[key][d] packed
  // via in-wave 4x4 transpose across lanes (l15&3).
  {
    float cb[4];
#pragma unroll
    for (int ni = 0; ni < 4; ++ni) cb[ni] = conv_b[w * 64 + ni * 16 + l15];
#pragma unroll
    for (int mi = 0; mi < 4; ++mi)
#pragma unroll
      for (int ni = 0; ni < 4; ++ni) {
        float v0 = fmaxf(acc[mi][ni][0] + cb[ni], 0.f);
        float v1 = fmaxf(acc[mi][ni][1] + cb[ni], 0.f);
        float v2 = fmaxf(acc[mi][ni][2] + cb[ni], 0.f);
        float v3 = fmaxf(acc[mi][ni][3] + cb[ni], 0.f);
        acc[mi][ni][0] = v0; acc[mi][ni][1] = v1;   // keep relu'd for ctT phase
        acc[mi][ni][2] = v2; acc[mi][ni][3] = v3;
        float t0 = __shfl_xor(v1, 1);
        float t1 = __shfl_xor(v0, 1);
        float t2 = __shfl_xor(v3, 1);
        float t3 = __shfl_xor(v2, 1);
        if (j4 & 1) { v0 = t0; v2 = t2; } else { v1 = t1; v3 = t3; }
        float u0 = __shfl_xor(v2, 2);
        float u1 = __shfl_xor(v3, 2);
        float u2 = __shfl_xor(v0, 2);
        float u3 = __shfl_xor(v1, 2);
        if (j4 & 2) { v0 = u0; v1 = u1; } else { v2 = u2; v3 = u3; }
        half4 h = {(_Float16)v0, (_Float16)v1, (_Float16)v2, (_Float16)v3};
        int key = mi * 16 + lq * 4 + j4;
        int dbase = w * 64 + ni * 16 + (l15 & ~3);
        *(half4*)(ctb + key * 1024 + ((dbase * 2) ^ ((key & 7) << 4))) = h;
      }
  }
  __syncthreads();   // B1: ct visible

  // ---------- Phase 2: scores^T[key][q] = (ct @ x^T) / sqrt(D)
  {
    const int mt = w & 3;
    const int nt0 = (w >> 2) * 2;
    f32x4 s0 = fzero, s1 = fzero;
    for (int ks = 0; ks < 16; ++ks) {
      int kb = ks * 64 + lq * 16;
      int key = mt * 16 + l15;
      half8 a = *(const half8*)(ctb + key * 1024 + (kb ^ ((key & 7) << 4)));
      int q0 = nt0 * 16 + l15;
      int sr0 = q0 + 1, sr1 = q0 + 17;
      half8 b0 = *(const half8*)(xsb + sr0 * 1024 + (kb ^ ((sr0 & 7) << 4)));
      half8 b1 = *(const half8*)(xsb + sr1 * 1024 + (kb ^ ((sr1 & 7) << 4)));
      s0 = __builtin_amdgcn_mfma_f32_16x16x32_f16(a, b0, s0, 0, 0, 0);
      s1 = __builtin_amdgcn_mfma_f32_16x16x32_f16(a, b1, s1, 0, 0, 0);
    }
    const float scale = 0.04419417382415922f;  // 1/sqrt(512)
#pragma unroll
    for (int r = 0; r < 4; ++r) { s0[r] *= scale; s1[r] *= scale; }
    int gran = mt * 4 + lq;
    int q0 = nt0 * 16 + l15, q1 = q0 + 16;
    *(f32x4*)(scb + q0 * 256 + ((gran * 16) ^ ((q0 & 15) << 4))) = s0;
    *(f32x4*)(scb + q1 * 256 + ((gran * 16) ^ ((q1 & 15) << 4))) = s1;
  }
  __syncthreads();   // B2: sc visible; ct/xs reads done

  // ---------- Phase 3a: softmax rows of sc -> P = softmax + I (fused residual)
  {
    int q = tid >> 3;
    int g = tid & 7;
    f32x4 va = *(const f32x4*)(scb + q * 256 + (((2 * g + 0) * 16) ^ ((q & 15) << 4)));
    f32x4 vb = *(const f32x4*)(scb + q * 256 + (((2 * g + 1) * 16) ^ ((q & 15) << 4)));
    float v[8] = {va[0], va[1], va[2], va[3], vb[0], vb[1], vb[2], vb[3]};
    float m = v[0];
#pragma unroll
    for (int i = 1; i < 8; ++i) m = fmaxf(m, v[i]);
    m = fmaxf(m, __shfl_xor(m, 1));
    m = fmaxf(m, __shfl_xor(m, 2));
    m = fmaxf(m, __shfl_xor(m, 4));
    float s = 0.f;
#pragma unroll
    for (int i = 0; i < 8; ++i) { v[i] = __expf(v[i] - m); s += v[i]; }
    s += __shfl_xor(s, 1);
    s += __shfl_xor(s, 2);
    s += __shfl_xor(s, 4);
    float inv = 1.f / s;
    half8 p;
#pragma unroll
    for (int i = 0; i < 8; ++i) {
      float pv = v[i] * inv + ((g * 8 + i == q) ? 1.f : 0.f);  // +I = fused residual
      p[i] = (_Float16)pv;
    }
    *(half8*)(Pb + q * 128 + ((g * 16) ^ ((q & 7) << 4))) = p;
  }

  // ---------- Phase 3b: ctT[512 d][64 key] into (dead) xs region from live acc
  {
    char* ctTb = xsb;
#pragma unroll
    for (int mi = 0; mi < 4; ++mi)
#pragma unroll
      for (int ni = 0; ni < 4; ++ni) {
        int t0 = mi * 16 + lq * 4;
        int d = w * 64 + ni * 16 + l15;
        half4 h = {(_Float16)acc[mi][ni][0], (_Float16)acc[mi][ni][1],
                   (_Float16)acc[mi][ni][2], (_Float16)acc[mi][ni][3]};
        *(half4*)(ctTb + d * 128 + ((t0 * 2) ^ ((d & 7) << 4))) = h;
      }
  }
  __syncthreads();   // B3: P, ctT visible

  // ---------- Phase 4: (P+I) @ ct -> pacc[q][d], LN stats, pool
  f32x4 pacc[4][4];
#pragma unroll
  for (int mi = 0; mi < 4; ++mi)
#pragma unroll
    for (int ni = 0; ni < 4; ++ni) pacc[mi][ni] = fzero;

  {
    char* ctTb = xsb;
#pragma unroll
    for (int ks = 0; ks < 2; ++ks) {
      half8 a[4], b[4];
#pragma unroll
      for (int mi = 0; mi < 4; ++mi) {
        int q = mi * 16 + l15;
        a[mi] = *(const half8*)(Pb + q * 128 + (((ks * 4 + lq) * 16) ^ ((q & 7) << 4)));
      }
#pragma unroll
      for (int ni = 0; ni < 4; ++ni) {
        int d = w * 64 + ni * 16 + l15;
        b[ni] = *(const half8*)(ctTb + d * 128 + (((ks * 4 + lq) * 16) ^ ((d & 7) << 4)));
      }
#pragma unroll
      for (int mi = 0; mi < 4; ++mi)
#pragma unroll
        for (int ni = 0; ni < 4; ++ni)
          pacc[mi][ni] = __builtin_amdgcn_mfma_f32_16x16x32_f16(a[mi], b[ni], pacc[mi][ni], 0, 0, 0);
    }
  }

  // per-row LN partial sums over this wave's 64 d-columns
#pragma unroll
  for (int mi = 0; mi < 4; ++mi)
#pragma unroll
    for (int r = 0; r < 4; ++r) {
      float s1 = 0.f, s2 = 0.f;
#pragma unroll
      for (int ni = 0; ni < 4; ++ni) {
        float v = pacc[mi][ni][r];
        s1 += v;
        s2 += v * v;
      }
      s1 += __shfl_xor(s1, 1); s2 += __shfl_xor(s2, 1);
      s1 += __shfl_xor(s1, 2); s2 += __shfl_xor(s2, 2);
      s1 += __shfl_xor(s1, 4); s2 += __shfl_xor(s2, 4);
      s1 += __shfl_xor(s1, 8); s2 += __shfl_xor(s2, 8);
      if (l15 == 0) {
        int t = mi * 16 + lq * 4 + r;
        rowpart[(t * 8 + w) * 2 + 0] = s1;
        rowpart[(t * 8 + w) * 2 + 1] = s2;
      }
    }
  __syncthreads();   // B4

  {
    int row = tid >> 3, p = tid & 7;
    float s1 = rowpart[(row * 8 + p) * 2 + 0];
    float s2 = rowpart[(row * 8 + p) * 2 + 1];
    s1 += __shfl_xor(s1, 1); s2 += __shfl_xor(s2, 1);
    s1 += __shfl_xor(s1, 2); s2 += __shfl_xor(s2, 2);
    s1 += __shfl_xor(s1, 4); s2 += __shfl_xor(s2, 4);
    if (p == 0) {
      float mu = s1 * (1.f / 512.f);
      float var = s2 * (1.f / 512.f) - mu * mu;
      mustat[row * 2 + 0] = mu;
      mustat[row * 2 + 1] = rsqrtf(var + 1e-5f);
    }
  }
  __syncthreads();   // B5

  // pooled[d] = g[d] * (1/64) * sum_q (v[q][d]-mu[q])*rs[q] + b[d]
#pragma unroll
  for (int ni = 0; ni < 4; ++ni) {
    float s = 0.f;
#pragma unroll
    for (int mi = 0; mi < 4; ++mi)
#pragma unroll
      for (int r = 0; r < 4; ++r) {
        int t = mi * 16 + lq * 4 + r;
        s += (pacc[mi][ni][r] - mustat[t * 2]) * mustat[t * 2 + 1];
      }
    s += __shfl_xor(s, 16);
    s += __shfl_xor(s, 32);
    if (l < 16) {
      int d = w * 64 + ni * 16 + l;
      out[(size_t)blk * 512 + d] = ln_g[d] * (s * (1.f / 64.f)) + ln_b[d];
    }
  }
}

extern "C" void kernel_launch(void* const* d_in, const int* in_sizes, int n_in,
                              void* d_out, int out_size, void* d_ws, size_t ws_size,
                              hipStream_t stream) {
  const float* x      = (const float*)d_in[0];
  const float* conv_w = (const float*)d_in[1];
  const float* conv_b = (const float*)d_in[2];
  const float* ln_g   = (const float*)d_in[3];
  const float* ln_b   = (const float*)d_in[4];
  float* out = (float*)d_out;
  _Float16* Wf = (_Float16*)d_ws;   // 512*1024 fp16 = 1 MB, fragment-ordered

  prep_w_kernel<<<(HID * HID * 2 + 255) / 256, 256, 0, stream>>>(conv_w, Wf);
  fused_kernel<<<NCHUNK, 512, 0, stream>>>(x, Wf, conv_b, ln_g, ln_b, out);
}